// Round 3
// baseline (260.604 us; speedup 1.0000x reference)
//
#include <hip/hip_runtime.h>
#include <stdint.h>

typedef __attribute__((ext_vector_type(8))) short bf16x8;   // 8 bf16 in 4 VGPRs
typedef __attribute__((ext_vector_type(4))) float f32x4;
typedef __attribute__((address_space(1))) void as1_void;
typedef __attribute__((address_space(3))) void as3_void;

#define D_MODEL 1024
#define SEQ     2048
#define BATCH   4
#define HEADS   16
#define HDIM    64

// softmax scale: exp(s/32) = exp2(s * log2e/32); folded into Wq/bq at prep time
#define QSCALE 0.045084220029218407f

__device__ __forceinline__ ushort f2bf(float f) {
  union { float f; unsigned u; } v; v.f = f;
  unsigned u = v.u + 0x7fffu + ((v.u >> 16) & 1u);  // RNE
  return (ushort)(u >> 16);
}

__device__ __forceinline__ void gload_lds16(const void* g, void* l) {
  // width=16: emits global_load_lds_dwordx4; LDS dest = wave-uniform base + lane*16
  __builtin_amdgcn_global_load_lds((as1_void*)(uintptr_t)g, (as3_void*)l, 16, 0, 0);
}

// pack 8 floats -> bf16x8 (truncation) via v_perm
__device__ __forceinline__ bf16x8 pack8(float a0, float a1, float a2, float a3,
                                        float a4, float a5, float a6, float a7) {
  union { uint u[4]; bf16x8 v; } x;
  x.u[0] = __builtin_amdgcn_perm(__float_as_uint(a1), __float_as_uint(a0), 0x07060302);
  x.u[1] = __builtin_amdgcn_perm(__float_as_uint(a3), __float_as_uint(a2), 0x07060302);
  x.u[2] = __builtin_amdgcn_perm(__float_as_uint(a5), __float_as_uint(a4), 0x07060302);
  x.u[3] = __builtin_amdgcn_perm(__float_as_uint(a7), __float_as_uint(a6), 0x07060302);
  return x.v;
}

// ---------- fused prep: X->bf16 | W transpose->bf16 (Wq scaled) | bias concat ----------
__global__ void prep_kernel(const float* __restrict__ X,
                            const float* w0, const float* w1, const float* w2, const float* w3,
                            const float* __restrict__ bq, const float* __restrict__ bk,
                            const float* __restrict__ bv,
                            ushort* __restrict__ Xb, ushort* __restrict__ WT,
                            float* __restrict__ bcat) {
  __shared__ float tile[32][33];
  const int bx = blockIdx.x, t = threadIdx.x;
  if (bx < 8192) {                       // X fp32 -> bf16, 8192*256 float4 groups
    int i = bx * 256 + t;
    float4 f = reinterpret_cast<const float4*>(X)[i];
    ushort4 o;
    o.x = f2bf(f.x); o.y = f2bf(f.y); o.z = f2bf(f.z); o.w = f2bf(f.w);
    reinterpret_cast<ushort4*>(Xb)[i] = o;
  } else if (bx < 12288) {               // weight transpose: 4 weights x 1024 tiles
    int tz = bx - 8192;
    int z = tz >> 10;
    int xy = tz & 1023;
    int bxt = xy & 31, byt = xy >> 5;
    const float* w = (z == 0) ? w0 : (z == 1) ? w1 : (z == 2) ? w2 : w3;
    const float sc = (z == 0) ? QSCALE : 1.0f;
    ushort* o = WT + (size_t)z * D_MODEL * D_MODEL;
    int tx = t & 31, ty = t >> 5;
    int x = bxt * 32 + tx;
    int y0 = byt * 32;
    #pragma unroll
    for (int i = ty; i < 32; i += 8)
      tile[i][tx] = w[(size_t)(y0 + i) * D_MODEL + x];
    __syncthreads();
    #pragma unroll
    for (int i = ty; i < 32; i += 8)
      o[(size_t)(bxt * 32 + i) * D_MODEL + y0 + tx] = f2bf(tile[tx][i] * sc);
  } else {                               // bias concat (12 blocks)
    int i = (bx - 12288) * 256 + t;
    bcat[i] = (i < 1024) ? bq[i] * QSCALE : (i < 2048) ? bk[i - 1024] : bv[i - 2048];
  }
}

#define MFMA16(a, b, c) __builtin_amdgcn_mfma_f32_16x16x32_bf16(a, b, c, 0, 0, 0)

// ---------- QKV GEMM, 256x256 8-phase template (T2 full 3-bit XOR swizzle + T3/T4 counted vmcnt + T5 setprio) ----------
// [8192,1024]@[1024,3072]; Q,K -> QK[8192][2048]; V -> Vt (permuted transpose).
// 512 threads = 8 waves (2M x 4N); BK=64; LDS = 2buf x (A 32KB + B 32KB) = 128 KiB.
// Bank math: row stride = 128 B = exactly 32 banks, so only the within-row column picks the
// bank. Swizzle: physical 16B-chunk = logical chunk ^ (row&7)  (byte ^= ((row&7)<<4)).
// Applied BOTH sides (rule 21): inverse-permuted GLOBAL source for global_load_lds (linear LDS
// dest) + the same XOR on every ds_read column.
// Per K-tile: 4 phases x {ds_read subtile | stage 1 half-tile | barrier | lgkmcnt(0) | 16 MFMA | barrier}.
// vmcnt never drains to 0 in the main loop: vmcnt(4) @ phase-1 end, vmcnt(2) @ phase-3 end.
__global__ __launch_bounds__(512, 2) void gemm_qkv(const ushort* __restrict__ A, const ushort* __restrict__ BT,
                                                   const float* __restrict__ bias,
                                                   ushort* __restrict__ QK, ushort* __restrict__ Vt) {
  __shared__ __align__(16) char smem[131072];   // [0,64K) = A bufs, [64K,128K) = B bufs
  const int tid  = threadIdx.x;
  const int w    = tid >> 6;
  const int lane = tid & 63;
  const int lo   = lane & 15, quad = lane >> 4;
  const int wr   = w >> 2, wc = w & 3;          // wave -> (row-half, col-quarter)

  // XCD-aware bijective swizzle (384 blocks, 384 % 8 == 0)
  const int orig = blockIdx.y * 12 + blockIdx.x;
  const int wg   = (orig & 7) * 48 + (orig >> 3);
  const int m0   = (wg / 12) * 256;
  const int n0   = (wg % 12) * 256;

  // staging: thread t writes linear LDS chunk t; physical chunk (row, pc) must hold logical
  // (row, pc ^ (row&7)) -> global source chunk = tid ^ ((tid>>3)&7)  (XOR touches low 3 bits only)
  const int tl = tid ^ ((tid >> 3) & 7);
  const ushort* sA = A  + (size_t)(m0 + (tl >> 3)) * 1024 + (tl & 7) * 8;
  const ushort* sB = BT + (size_t)(n0 + (tl >> 3)) * 1024 + (tl & 7) * 8;
  char* lw = smem + w * 1024;                   // per-wave stage base (HW adds lane*16)

  // swizzled ds_read: addr = row*128 + ((ks*64 + quad*16) ^ ((row&7)<<4)); row&7 == lo&7
  const int o0 = (quad * 16) ^ ((lo & 7) << 4);   // ks=0 column
  const int o1 = o0 ^ 64;                          // ks=1 column
  const int rdA = wr * 16384 + lo * 128;           // + b32 + mi*2048 + o{0,1}
  const int rdB = 65536 + (wc * 64 + lo) * 128;    // + b32 + ni*2048 + o{0,1}

  f32x4 acc[8][4];
  #pragma unroll
  for (int i = 0; i < 8; ++i)
    #pragma unroll
    for (int j = 0; j < 4; ++j) acc[i][j] = {0.f, 0.f, 0.f, 0.f};

  // ---- prologue: stage tile 0 into buf 0; order = loop issue order ----
  gload_lds16(sB,              lw + 65536);            // B h0 rb0
  gload_lds16(sB +  64 * 1024, lw + 65536 +  8192);    // B h0 rb1
  gload_lds16(sB + 128 * 1024, lw + 65536 + 16384);    // B h1 rb0
  gload_lds16(sB + 192 * 1024, lw + 65536 + 24576);    // B h1 rb1
  gload_lds16(sA,              lw);                    // A h0 rb0
  gload_lds16(sA + 128 * 1024, lw + 16384);            // A h1 rb0
  gload_lds16(sA +  64 * 1024, lw +  8192);            // A h0 rb1
  gload_lds16(sA + 192 * 1024, lw + 24576);            // A h1 rb1
  asm volatile("s_waitcnt vmcnt(2)" ::: "memory");     // rb1 A-calls stay in flight
  __builtin_amdgcn_s_barrier();
  asm volatile("" ::: "memory");

  const char* L = smem;
  #pragma unroll 2
  for (int kt = 0; kt < 16; ++kt) {
    const int b32 = (kt & 1) << 15;
    const int nb  = b32 ^ 32768;
    const int kc  = (kt + 1) * 64;
    const bool pf = kt < 15;
    bf16x8 bfr[4][2], af0[2], af1[2];

    // ================ phase 0: all B frags + A mi{0,1}; stage B h0 ================
    #pragma unroll
    for (int ni = 0; ni < 4; ++ni) {
      bfr[ni][0] = *(const bf16x8*)(L + b32 + rdB + ni * 2048 + o0);
      bfr[ni][1] = *(const bf16x8*)(L + b32 + rdB + ni * 2048 + o1);
    }
    af0[0] = *(const bf16x8*)(L + b32 + rdA + o0);
    af0[1] = *(const bf16x8*)(L + b32 + rdA + o1);
    af1[0] = *(const bf16x8*)(L + b32 + rdA + 2048 + o0);
    af1[1] = *(const bf16x8*)(L + b32 + rdA + 2048 + o1);
    if (pf) {
      gload_lds16(sB + kc,             lw + nb + 65536);
      gload_lds16(sB + 64 * 1024 + kc, lw + nb + 65536 + 8192);
    }
    asm volatile("s_waitcnt lgkmcnt(8)" ::: "memory");
    __builtin_amdgcn_s_barrier();
    asm volatile("s_waitcnt lgkmcnt(0)" ::: "memory");
    __builtin_amdgcn_sched_barrier(0);
    __builtin_amdgcn_s_setprio(1);
    #pragma unroll
    for (int ks = 0; ks < 2; ++ks)
      #pragma unroll
      for (int ni = 0; ni < 4; ++ni) {
        acc[0][ni] = MFMA16(af0[ks], bfr[ni][ks], acc[0][ni]);
        acc[1][ni] = MFMA16(af1[ks], bfr[ni][ks], acc[1][ni]);
      }
    __builtin_amdgcn_s_setprio(0);
    __builtin_amdgcn_s_barrier();
    asm volatile("" ::: "memory");

    // ================ phase 1: A mi{2,3}; stage B h1; vmcnt(4) ================
    af0[0] = *(const bf16x8*)(L + b32 + rdA + 2 * 2048 + o0);
    af0[1] = *(const bf16x8*)(L + b32 + rdA + 2 * 2048 + o1);
    af1[0] = *(const bf16x8*)(L + b32 + rdA + 3 * 2048 + o0);
    af1[1] = *(const bf16x8*)(L + b32 + rdA + 3 * 2048 + o1);
    if (pf) {
      gload_lds16(sB + 128 * 1024 + kc, lw + nb + 65536 + 16384);
      gload_lds16(sB + 192 * 1024 + kc, lw + nb + 65536 + 24576);
    }
    __builtin_amdgcn_s_barrier();
    asm volatile("s_waitcnt lgkmcnt(0)" ::: "memory");
    __builtin_amdgcn_sched_barrier(0);
    __builtin_amdgcn_s_setprio(1);
    #pragma unroll
    for (int ks = 0; ks < 2; ++ks)
      #pragma unroll
      for (int ni = 0; ni < 4; ++ni) {
        acc[2][ni] = MFMA16(af0[ks], bfr[ni][ks], acc[2][ni]);
        acc[3][ni] = MFMA16(af1[ks], bfr[ni][ks], acc[3][ni]);
      }
    __builtin_amdgcn_s_setprio(0);
    if (pf) asm volatile("s_waitcnt vmcnt(4)" ::: "memory");
    else    asm volatile("s_waitcnt vmcnt(0)" ::: "memory");
    __builtin_amdgcn_s_barrier();
    asm volatile("" ::: "memory");

    // ================ phase 2: A mi{4,5}; stage A rb0 ================
    af0[0] = *(const bf16x8*)(L + b32 + rdA + 4 * 2048 + o0);
    af0[1] = *(const bf16x8*)(L + b32 + rdA + 4 * 2048 + o1);
    af1[0] = *(const bf16x8*)(L + b32 + rdA + 5 * 2048 + o0);
    af1[1] = *(const bf16x8*)(L + b32 + rdA + 5 * 2048 + o1);
    if (pf) {
      gload_lds16(sA + kc,              lw + nb);
      gload_lds16(sA + 128 * 1024 + kc, lw + nb + 16384);
    }
    __builtin_amdgcn_s_barrier();
    asm volatile("s_waitcnt lgkmcnt(0)" ::: "memory");
    __builtin_amdgcn_sched_barrier(0);
    __builtin_amdgcn_s_setprio(1);
    #pragma unroll
    for (int ks = 0; ks < 2; ++ks)
      #pragma unroll
      for (int ni = 0; ni < 4; ++ni) {
        acc[4][ni] = MFMA16(af0[ks], bfr[ni][ks], acc[4][ni]);
        acc[5][ni] = MFMA16(af1[ks], bfr[ni][ks], acc[5][ni]);
      }
    __builtin_amdgcn_s_setprio(0);
    __builtin_amdgcn_s_barrier();
    asm volatile("" ::: "memory");

    // ================ phase 3: A mi{6,7}; stage A rb1; vmcnt(2) ================
    af0[0] = *(const bf16x8*)(L + b32 + rdA + 6 * 2048 + o0);
    af0[1] = *(const bf16x8*)(L + b32 + rdA + 6 * 2048 + o1);
    af1[0] = *(const bf16x8*)(L + b32 + rdA + 7 * 2048 + o0);
    af1[1] = *(const bf16x8*)(L + b32 + rdA + 7 * 2048 + o1);
    if (pf) {
      gload_lds16(sA + 64 * 1024 + kc,  lw + nb + 8192);
      gload_lds16(sA + 192 * 1024 + kc, lw + nb + 24576);
    }
    __builtin_amdgcn_s_barrier();
    asm volatile("s_waitcnt lgkmcnt(0)" ::: "memory");
    __builtin_amdgcn_sched_barrier(0);
    __builtin_amdgcn_s_setprio(1);
    #pragma unroll
    for (int ks = 0; ks < 2; ++ks)
      #pragma unroll
      for (int ni = 0; ni < 4; ++ni) {
        acc[6][ni] = MFMA16(af0[ks], bfr[ni][ks], acc[6][ni]);
        acc[7][ni] = MFMA16(af1[ks], bfr[ni][ks], acc[7][ni]);
      }
    __builtin_amdgcn_s_setprio(0);
    if (pf) asm volatile("s_waitcnt vmcnt(2)" ::: "memory");
    __builtin_amdgcn_s_barrier();
    asm volatile("" ::: "memory");
  }

  // ---- epilogue ----
  if (n0 < 2048) {
    // Q,K part: dense [8192][2048] store
    #pragma unroll
    for (int ni = 0; ni < 4; ++ni) {
      const int col = n0 + wc * 64 + ni * 16 + lo;
      const float bv = bias[col];
      #pragma unroll
      for (int mi = 0; mi < 8; ++mi) {
        const int row = m0 + wr * 128 + mi * 16 + quad * 4;
        #pragma unroll
        for (int r = 0; r < 4; ++r)
          QK[(size_t)(row + r) * 2048 + col] = f2bf(acc[mi][ni][r] + bv);
      }
    }
  } else {
    // V part: permuted-transpose store into Vt[b][h][d][SEQ]
    #pragma unroll
    for (int ni = 0; ni < 4; ++ni) {
      const int col  = n0 + wc * 64 + ni * 16 + lo;
      const int vcol = col - 2048;
      const int hh = vcol >> 6, d = vcol & 63;
      const float bv = bias[col];
      #pragma unroll
      for (int mi = 0; mi < 8; ++mi) {
        const int base = m0 + wr * 128 + mi * 16;        // multiple of 16
        const int brow = base + quad * 4;                // 4 keys brow..brow+3
        const int bidx = brow >> 11;                     // batch
        const int srow = brow & 2047;                    // seq within batch
        const int ck   = srow >> 6;
        const int c0   = (base & 32) + (quad << 3) + ((base >> 2) & 4);
        ushort e0 = f2bf(acc[mi][ni][0] + bv);
        ushort e1 = f2bf(acc[mi][ni][1] + bv);
        ushort e2 = f2bf(acc[mi][ni][2] + bv);
        ushort e3 = f2bf(acc[mi][ni][3] + bv);
        uint2 pk;
        pk.x = (uint)e0 | ((uint)e1 << 16);
        pk.y = (uint)e2 | ((uint)e3 << 16);
        *(uint2*)&Vt[(size_t)((bidx * HEADS + hh) * HDIM + d) * SEQ + ck * 64 + c0] = pk;
      }
    }
  }
}

// ---------- m97-style GEMM (final projection): C[M][N] = A@BT^T + bias, fp32 out ----------
__global__ __launch_bounds__(256) void gemm_bt_f32(const ushort* __restrict__ A, const ushort* __restrict__ BT,
                                                   const float* __restrict__ bias, float* __restrict__ C,
                                                   int M, int N, int K) {
  __shared__ __align__(16) ushort As[128 * 32];
  __shared__ __align__(16) ushort Bs[128 * 32];
  const int tid  = threadIdx.x;
  const int w    = tid >> 6;
  const int lane = tid & 63;
  const int lo   = lane & 15, quad = lane >> 4;
  const int m0 = blockIdx.y * 128, n0 = blockIdx.x * 128;
  const int ra = lane >> 2;
  const int ca = (lane & 3) * 8;
  const int wm = (w & 1) * 64, wn = (w >> 1) * 64;

  f32x4 acc[4][4];
  #pragma unroll
  for (int i = 0; i < 4; ++i)
    #pragma unroll
    for (int j = 0; j < 4; ++j) acc[i][j] = {0.f, 0.f, 0.f, 0.f};

  for (int k0 = 0; k0 < K; k0 += 32) {
    #pragma unroll
    for (int i = 0; i < 2; ++i) {
      const int j = w * 2 + i;
      gload_lds16(A  + (size_t)(m0 + j * 16 + ra) * K + k0 + ca, &As[j * 512]);
      gload_lds16(BT + (size_t)(n0 + j * 16 + ra) * K + k0 + ca, &Bs[j * 512]);
    }
    __syncthreads();
    bf16x8 af[4], bfv[4];
    #pragma unroll
    for (int mi = 0; mi < 4; ++mi) af[mi]  = *(const bf16x8*)&As[(wm + mi * 16 + lo) * 32 + quad * 8];
    #pragma unroll
    for (int ni = 0; ni < 4; ++ni) bfv[ni] = *(const bf16x8*)&Bs[(wn + ni * 16 + lo) * 32 + quad * 8];
    #pragma unroll
    for (int mi = 0; mi < 4; ++mi)
      #pragma unroll
      for (int ni = 0; ni < 4; ++ni)
        acc[mi][ni] = __builtin_amdgcn_mfma_f32_16x16x32_bf16(af[mi], bfv[ni], acc[mi][ni], 0, 0, 0);
    __syncthreads();
  }

  #pragma unroll
  for (int ni = 0; ni < 4; ++ni) {
    const int col = n0 + wn + ni * 16 + lo;
    const float bv = bias[col];
    #pragma unroll
    for (int mi = 0; mi < 4; ++mi) {
      #pragma unroll
      for (int r = 0; r < 4; ++r) {
        const int row = m0 + wm + mi * 16 + quad * 4 + r;
        C[(size_t)row * N + col] = acc[mi][ni][r] + bv;
      }
    }
  }
}

// ---------- flash attention: block = 256 q rows, wave = 64 q (4 qg x 16), 64-key chunks ----------
// S^T via mfma(A=K,B=Q); exp'd scores feed PV A-operand directly from registers.
// R3: (a) double-buffered K/V staging with counted vmcnt (T3/T14): chunk ck+1's loads are
// issued at the top of iteration ck and only waited one iteration later (vmcnt(4) = the 4
// just-issued calls stay in flight; never drains to 0 in the loop); raw s_barrier, no
// __syncthreads drain. (b) XCD-aware block remap (T1): all 8 q-blocks of group G=b*16+h get
// physical id p with p&7 == G&7 -> same XCD L2, K/V (512 KB/group) fetched once per XCD.
// (c) setprio(1) around the pure-MFMA PV cluster (T5, m191).
__global__ __launch_bounds__(256, 2) void attn_kernel(const ushort* __restrict__ QK,
                                                      const ushort* __restrict__ Vt,
                                                      ushort* __restrict__ Og) {
  __shared__ __align__(16) ushort Ks[2][64 * 64];   // [buf][key][64 d], seg-swizzled
  __shared__ __align__(16) ushort Vs[2][64 * 64];   // [buf][d][64 key-slots], seg-swizzled

  const int tid  = threadIdx.x;
  const int w    = tid >> 6, lane = tid & 63;
  const int lo   = lane & 15, quad = lane >> 4;

  // XCD remap: p -> (G, qb); bijective, p&7 == G&7 (8 q-blocks of a group share an XCD)
  const int p  = blockIdx.x + (blockIdx.y << 3) + (blockIdx.z << 7);
  const int G  = ((p >> 6) << 3) | (p & 7);
  const int h  = G & 15, b = G >> 4;
  const int qbase = ((p >> 3) & 7) * 256 + w * 64;
  const int swz = lo & 7;

  // per-thread staging geometry (4 gload_lds16 per chunk: K0,V0,K1,V1)
  auto STAGE = [&](int buf, int ck) {
    #pragma unroll
    for (int i = 0; i < 2; ++i) {
      const int c16 = (w * 2 + i) * 64 + lane;
      const int r = c16 >> 3, ps = c16 & 7;
      const int gs = ps ^ (r & 7);
      gload_lds16(QK + (size_t)(b * SEQ + ck * 64 + r) * 2048 + 1024 + h * HDIM + gs * 8,
                  &Ks[buf][(w * 2 + i) * 512]);
      gload_lds16(Vt + (size_t)((b * HEADS + h) * HDIM + r) * SEQ + ck * 64 + gs * 8,
                  &Vs[buf][(w * 2 + i) * 512]);
    }
  };

  // Q fragments (B-operand layout: n=lo, k=quad*8+j); pre-scaled by QSCALE via Wq
  bf16x8 qf[4][2];
  #pragma unroll
  for (int qg = 0; qg < 4; ++qg) {
    const ushort* qp = QK + (size_t)(b * SEQ + qbase + qg * 16 + lo) * 2048 + h * HDIM;
    qf[qg][0] = *(const bf16x8*)(qp + quad * 8);
    qf[qg][1] = *(const bf16x8*)(qp + 32 + quad * 8);
  }

  f32x4 acc[4][4];
  #pragma unroll
  for (int qg = 0; qg < 4; ++qg)
    #pragma unroll
    for (int t = 0; t < 4; ++t) acc[qg][t] = {0.f, 0.f, 0.f, 0.f};
  float lsum[4] = {0.f, 0.f, 0.f, 0.f};

  // prologue: stage chunk 0 into buf 0; drain everything (incl. Q loads) once
  STAGE(0, 0);
  __syncthreads();

  #pragma unroll 2
  for (int ck = 0; ck < SEQ / 64; ++ck) {
    const int cur = ck & 1;
    if (ck < SEQ / 64 - 1) {
      STAGE(cur ^ 1, ck + 1);                           // issue-early (T14)
      asm volatile("s_waitcnt vmcnt(4)" ::: "memory");  // wait cur; next stays in flight
    } else {
      asm volatile("s_waitcnt vmcnt(0)" ::: "memory");
    }
    __builtin_amdgcn_s_barrier();
    asm volatile("" ::: "memory");

    // --- phase A: K fragments resident, S^T per q-group, exp + pack in registers ---
    bf16x8 kf[4][2];
    #pragma unroll
    for (int sub = 0; sub < 4; ++sub) {
      const ushort* kr = &Ks[cur][(sub * 16 + lo) * 64];
      kf[sub][0] = *(const bf16x8*)(kr + ((quad ^ swz) * 8));
      kf[sub][1] = *(const bf16x8*)(kr + (((4 + quad) ^ swz) * 8));
    }

    bf16x8 af[4][2];
    #pragma unroll
    for (int qg = 0; qg < 4; ++qg) {
      f32x4 s[4];
      #pragma unroll
      for (int sub = 0; sub < 4; ++sub) s[sub] = {0.f, 0.f, 0.f, 0.f};
      #pragma unroll
      for (int sub = 0; sub < 4; ++sub) {
        s[sub] = __builtin_amdgcn_mfma_f32_16x16x32_bf16(kf[sub][0], qf[qg][0], s[sub], 0, 0, 0);
        s[sub] = __builtin_amdgcn_mfma_f32_16x16x32_bf16(kf[sub][1], qf[qg][1], s[sub], 0, 0, 0);
      }
      float p2[4][4];
      #pragma unroll
      for (int sub = 0; sub < 4; ++sub)
        #pragma unroll
        for (int r = 0; r < 4; ++r) p2[sub][r] = __builtin_amdgcn_exp2f(s[sub][r]);
      float t0 = 0.f;
      #pragma unroll
      for (int sub = 0; sub < 4; ++sub)
        t0 += (p2[sub][0] + p2[sub][1]) + (p2[sub][2] + p2[sub][3]);
      lsum[qg] += t0;
      af[qg][0] = pack8(p2[0][0], p2[0][1], p2[0][2], p2[0][3], p2[1][0], p2[1][1], p2[1][2], p2[1][3]);
      af[qg][1] = pack8(p2[2][0], p2[2][1], p2[2][2], p2[2][3], p2[3][0], p2[3][1], p2[3][2], p2[3][3]);
    }

    // --- phase B: PV (A = exp'd scores from registers, B = V^T from LDS) ---
    __builtin_amdgcn_s_setprio(1);
    #pragma unroll
    for (int t = 0; t < 4; ++t) {
      const ushort* vr = &Vs[cur][(t * 16 + lo) * 64];
      #pragma unroll
      for (int hh = 0; hh < 2; ++hh) {
        bf16x8 vf = *(const bf16x8*)(vr + (((hh * 4 + quad) ^ swz) * 8));
        #pragma unroll
        for (int qg = 0; qg < 4; ++qg)
          acc[qg][t] = __builtin_amdgcn_mfma_f32_16x16x32_bf16(af[qg][hh], vf, acc[qg][t], 0, 0, 0);
      }
    }
    __builtin_amdgcn_s_setprio(0);

    asm volatile("" ::: "memory");
    __builtin_amdgcn_s_barrier();   // all reads of buf cur done before it is restaged
    asm volatile("" ::: "memory");
  }

  // --- epilogue: lsum lives at lane lo = q; reduce across quads, redistribute, store ---
  #pragma unroll
  for (int qg = 0; qg < 4; ++qg) {
    float v = lsum[qg];
    v += __shfl_xor(v, 16);
    v += __shfl_xor(v, 32);
    float linv[4];
    #pragma unroll
    for (int r = 0; r < 4; ++r) linv[r] = 1.0f / __shfl(v, quad * 4 + r);
    #pragma unroll
    for (int t = 0; t < 4; ++t)
      #pragma unroll
      for (int r = 0; r < 4; ++r)
        Og[(size_t)(b * SEQ + qbase + qg * 16 + quad * 4 + r) * D_MODEL + h * HDIM + t * 16 + lo] =
            f2bf(acc[qg][t][r] * linv[r]);
  }
}

extern "C" void kernel_launch(void* const* d_in, const int* in_sizes, int n_in,
                              void* d_out, int out_size, void* d_ws, size_t ws_size,
                              hipStream_t stream) {
  const float* X  = (const float*)d_in[0];
  const float* Wq = (const float*)d_in[1];
  const float* bq = (const float*)d_in[2];
  const float* Wk = (const float*)d_in[3];
  const float* bk = (const float*)d_in[4];
  const float* Wv = (const float*)d_in[5];
  const float* bv = (const float*)d_in[6];
  const float* Wo = (const float*)d_in[7];
  const float* bo = (const float*)d_in[8];
  float* out = (float*)d_out;
  char* ws = (char*)d_ws;

  // workspace (88 MB):
  //   [0,16M)   Xb  (bf16 X)
  //   [16,24M)  WT  (4x bf16 transposed weights q|k|v|o; Wq pre-scaled)
  //   [24,56M)  QK  bf16 [8192][2048]
  //   [56,72M)  Vt  bf16 [b][h][64][2048] (permuted keys)
  //   [72,88M)  Ob  bf16 [8192][1024]; head transiently holds bcat (dead before attn writes Ob)
  ushort* Xb  = (ushort*)(ws);
  ushort* WT  = (ushort*)(ws + 16777216);
  ushort* QKb = (ushort*)(ws + 25165824);
  ushort* Vtb = (ushort*)(ws + 58720256);
  ushort* Ob  = (ushort*)(ws + 75497472);
  float*  bcat = (float*)(ws + 75497472);
  const int WSTRIDE = D_MODEL * D_MODEL;

  // 1) fused prep: X->bf16, weight transposes, bias concat
  prep_kernel<<<12300, 256, 0, stream>>>(X, Wq, Wk, Wv, Wo, bq, bk, bv, Xb, WT, bcat);

  // 2) fused QKV projection (256^2 8-phase, 3-bit XOR swizzle); V written straight to Vt
  gemm_qkv<<<dim3(12, 32), 512, 0, stream>>>(Xb, WT, bcat, QKb, Vtb);

  // 3) flash attention (double-buffered staging + XCD-grouped K/V reuse)
  attn_kernel<<<dim3(SEQ / 256, HEADS, BATCH), 256, 0, stream>>>(QKb, Vtb, Ob);

  // 4) output projection (fp32 out + bias)
  gemm_bt_f32<<<dim3(8, 64), 256, 0, stream>>>(Ob, WT + 3 * WSTRIDE, bo, out,
                                               BATCH * SEQ, D_MODEL, D_MODEL);
}

// Round 4
// 249.895 us; speedup vs baseline: 1.0429x; 1.0429x over previous
//
#include <hip/hip_runtime.h>
#include <stdint.h>

typedef __attribute__((ext_vector_type(8))) short bf16x8;   // 8 bf16 in 4 VGPRs
typedef __attribute__((ext_vector_type(4))) float f32x4;
typedef __attribute__((address_space(1))) void as1_void;
typedef __attribute__((address_space(3))) void as3_void;

#define D_MODEL 1024
#define SEQ     2048
#define BATCH   4
#define HEADS   16
#define HDIM    64

// softmax scale: exp(s/32) = exp2(s * log2e/32); folded into Wq/bq at prep time
#define QSCALE 0.045084220029218407f

__device__ __forceinline__ ushort f2bf(float f) {
  union { float f; unsigned u; } v; v.f = f;
  unsigned u = v.u + 0x7fffu + ((v.u >> 16) & 1u);  // RNE
  return (ushort)(u >> 16);
}

__device__ __forceinline__ void gload_lds16(const void* g, void* l) {
  // width=16: emits global_load_lds_dwordx4; LDS dest = wave-uniform base + lane*16
  __builtin_amdgcn_global_load_lds((as1_void*)(uintptr_t)g, (as3_void*)l, 16, 0, 0);
}

// pack 8 floats -> bf16x8 (truncation) via v_perm
__device__ __forceinline__ bf16x8 pack8(float a0, float a1, float a2, float a3,
                                        float a4, float a5, float a6, float a7) {
  union { uint u[4]; bf16x8 v; } x;
  x.u[0] = __builtin_amdgcn_perm(__float_as_uint(a1), __float_as_uint(a0), 0x07060302);
  x.u[1] = __builtin_amdgcn_perm(__float_as_uint(a3), __float_as_uint(a2), 0x07060302);
  x.u[2] = __builtin_amdgcn_perm(__float_as_uint(a5), __float_as_uint(a4), 0x07060302);
  x.u[3] = __builtin_amdgcn_perm(__float_as_uint(a7), __float_as_uint(a6), 0x07060302);
  return x.v;
}

// ---------- fused prep: X->bf16 | W transpose->bf16 (Wq scaled) | bias concat ----------
__global__ void prep_kernel(const float* __restrict__ X,
                            const float* w0, const float* w1, const float* w2, const float* w3,
                            const float* __restrict__ bq, const float* __restrict__ bk,
                            const float* __restrict__ bv,
                            ushort* __restrict__ Xb, ushort* __restrict__ WT,
                            float* __restrict__ bcat) {
  __shared__ float tile[32][33];
  const int bx = blockIdx.x, t = threadIdx.x;
  if (bx < 8192) {                       // X fp32 -> bf16, 8192*256 float4 groups
    int i = bx * 256 + t;
    float4 f = reinterpret_cast<const float4*>(X)[i];
    ushort4 o;
    o.x = f2bf(f.x); o.y = f2bf(f.y); o.z = f2bf(f.z); o.w = f2bf(f.w);
    reinterpret_cast<ushort4*>(Xb)[i] = o;
  } else if (bx < 12288) {               // weight transpose: 4 weights x 1024 tiles
    int tz = bx - 8192;
    int z = tz >> 10;
    int xy = tz & 1023;
    int bxt = xy & 31, byt = xy >> 5;
    const float* w = (z == 0) ? w0 : (z == 1) ? w1 : (z == 2) ? w2 : w3;
    const float sc = (z == 0) ? QSCALE : 1.0f;
    ushort* o = WT + (size_t)z * D_MODEL * D_MODEL;
    int tx = t & 31, ty = t >> 5;
    int x = bxt * 32 + tx;
    int y0 = byt * 32;
    #pragma unroll
    for (int i = ty; i < 32; i += 8)
      tile[i][tx] = w[(size_t)(y0 + i) * D_MODEL + x];
    __syncthreads();
    #pragma unroll
    for (int i = ty; i < 32; i += 8)
      o[(size_t)(bxt * 32 + i) * D_MODEL + y0 + tx] = f2bf(tile[tx][i] * sc);
  } else {                               // bias concat (12 blocks)
    int i = (bx - 12288) * 256 + t;
    bcat[i] = (i < 1024) ? bq[i] * QSCALE : (i < 2048) ? bk[i - 1024] : bv[i - 2048];
  }
}

#define MFMA16(a, b, c) __builtin_amdgcn_mfma_f32_16x16x32_bf16(a, b, c, 0, 0, 0)

// ---------- generalized 8-phase GEMM template: 256 x BN tiles, K=1024, BK=64 ----------
// 512 threads = 8 waves (2M x 4N); LDS = 2buf x (A 32KB + B BN*128B).
// Grids sized to exact multiples of 256 CUs: BN=192 -> 512 blocks (2 full rounds, no tail);
// BN=128 -> 256 blocks (1 full round).  T2 3-bit XOR swizzle both-sides; T3/T4 counted vmcnt
// (vmcnt(4) @ph1, vmcnt(2) @ph3 -- never 0 in the loop); T5 setprio around MFMA clusters.
// Stage order per K-tile (for tile kt+1): NI==3: [B0,B1 |ph0| B2,A0 |ph1| A2 |ph2| A1,A3 |ph3|]
//                                          NI==2: [B0,B1 |ph0| A0,A2 |ph1| A1 |ph2| A3 |ph3|]
// Crossing invariant: first NB+2 calls (B*, A-rows for ph0/ph1) complete at tile entry, the
// 2 calls covering A rows 64-127/192-255 (read only at ph2/ph3) retire via vmcnt(4) @ph1.
// F32OUT=false: QKV epilogue (Q,K dense bf16 + V permuted transpose), branch per 16-col group
// (2048 % 16 == 0 -> wave-uniform).  F32OUT=true: fp32 C + bias.
template <int BN, bool F32OUT>
__global__ __launch_bounds__(512, 2) void gemm8p(const ushort* __restrict__ A,
                                                 const ushort* __restrict__ BT,
                                                 const float* __restrict__ bias,
                                                 ushort* __restrict__ QK,
                                                 ushort* __restrict__ Vt,
                                                 float* __restrict__ Cf) {
  constexpr int NI = BN / 64;            // B frags per wave = B stage-calls per K-tile
  constexpr int BB = BN * 128;           // B K-tile buffer bytes (BN rows x 64 x 2B)
  constexpr int WCOL = BN / 4;           // cols per wave
  __shared__ __align__(16) char smem[65536 + 2 * BB];   // [0,64K)=A bufs, [64K,..)=B bufs
  const int tid  = threadIdx.x;
  const int w    = tid >> 6;
  const int lane = tid & 63;
  const int lo   = lane & 15, quad = lane >> 4;
  const int wr   = w >> 2, wc = w & 3;

  // XCD-aware bijective swizzle (nwg % 8 == 0 for both instantiations)
  const int nx   = gridDim.x;
  const int nwg  = nx * gridDim.y;
  const int orig = blockIdx.y * nx + blockIdx.x;
  const int wg   = (orig & 7) * (nwg >> 3) + (orig >> 3);
  const int m0   = (wg / nx) * 256;
  const int n0   = (wg % nx) * BN;

  // staging: thread t writes linear LDS chunk t; physical chunk (row, pc) holds logical
  // (row, pc ^ (row&7)) -> global source chunk = tid ^ ((tid>>3)&7)  (XOR in low 3 bits only)
  const int tl = tid ^ ((tid >> 3) & 7);
  const ushort* sA = A  + (size_t)(m0 + (tl >> 3)) * 1024 + (tl & 7) * 8;
  const ushort* sB = BT + (size_t)(n0 + (tl >> 3)) * 1024 + (tl & 7) * 8;
  char* lwA = smem + w * 1024;                 // per-wave stage base (HW adds lane*16)
  char* lwB = smem + 65536 + w * 1024;

  // swizzled ds_read: addr = row*128 + ((ks*64 + quad*16) ^ ((row&7)<<4)); row&7 == lo&7
  const int o0 = (quad * 16) ^ ((lo & 7) << 4);
  const int o1 = o0 ^ 64;
  const int rdA = wr * 16384 + lo * 128;           // + b32A + mi*2048 + o{0,1}
  const int rdB = 65536 + (wc * WCOL + lo) * 128;  // + b32B + ni*2048 + o{0,1}

  f32x4 acc[8][NI];
  #pragma unroll
  for (int i = 0; i < 8; ++i)
    #pragma unroll
    for (int j = 0; j < NI; ++j) acc[i][j] = {0.f, 0.f, 0.f, 0.f};

  // ---- prologue: stage tile 0 into buf 0; order = loop issue order ----
  gload_lds16(sB,               lwB);                  // B0
  gload_lds16(sB +  64 * 1024,  lwB +  8192);          // B1
  if constexpr (NI == 3) gload_lds16(sB + 128 * 1024, lwB + 16384);   // B2
  gload_lds16(sA,               lwA);                  // A0 (rows 0-63)
  gload_lds16(sA + 128 * 1024,  lwA + 16384);          // A2 (rows 128-191)
  gload_lds16(sA +  64 * 1024,  lwA +  8192);          // A1 (rows 64-127)
  gload_lds16(sA + 192 * 1024,  lwA + 24576);          // A3 (rows 192-255)
  asm volatile("s_waitcnt vmcnt(2)" ::: "memory");     // A1,A3 stay in flight (read @ph2/ph3)
  __builtin_amdgcn_s_barrier();
  asm volatile("" ::: "memory");

  const char* L = smem;
  #pragma unroll 2
  for (int kt = 0; kt < 16; ++kt) {
    const int b32A = (kt & 1) << 15;
    const int b32B = (kt & 1) * BB;
    const int nbA  = b32A ^ 32768;
    const int nbB  = b32B ^ BB;
    const int kc   = (kt + 1) * 64;
    const bool pf  = kt < 15;
    bf16x8 bfr[NI][2], af0[2], af1[2];

    // ================ phase 0: all B frags + A mi{0,1}; stage B0,B1 ================
    #pragma unroll
    for (int ni = 0; ni < NI; ++ni) {
      bfr[ni][0] = *(const bf16x8*)(L + b32B + rdB + ni * 2048 + o0);
      bfr[ni][1] = *(const bf16x8*)(L + b32B + rdB + ni * 2048 + o1);
    }
    af0[0] = *(const bf16x8*)(L + b32A + rdA + o0);
    af0[1] = *(const bf16x8*)(L + b32A + rdA + o1);
    af1[0] = *(const bf16x8*)(L + b32A + rdA + 2048 + o0);
    af1[1] = *(const bf16x8*)(L + b32A + rdA + 2048 + o1);
    if (pf) {
      gload_lds16(sB + kc,             lwB + nbB);
      gload_lds16(sB + 64 * 1024 + kc, lwB + nbB + 8192);
    }
    asm volatile("s_waitcnt lgkmcnt(8)" ::: "memory");
    __builtin_amdgcn_s_barrier();
    asm volatile("s_waitcnt lgkmcnt(0)" ::: "memory");
    __builtin_amdgcn_sched_barrier(0);
    __builtin_amdgcn_s_setprio(1);
    #pragma unroll
    for (int ks = 0; ks < 2; ++ks)
      #pragma unroll
      for (int ni = 0; ni < NI; ++ni) {
        acc[0][ni] = MFMA16(af0[ks], bfr[ni][ks], acc[0][ni]);
        acc[1][ni] = MFMA16(af1[ks], bfr[ni][ks], acc[1][ni]);
      }
    __builtin_amdgcn_s_setprio(0);
    __builtin_amdgcn_s_barrier();
    asm volatile("" ::: "memory");

    // ================ phase 1: A mi{2,3}; stage (B2,A0)|(A0,A2); vmcnt(4) ================
    af0[0] = *(const bf16x8*)(L + b32A + rdA + 2 * 2048 + o0);
    af0[1] = *(const bf16x8*)(L + b32A + rdA + 2 * 2048 + o1);
    af1[0] = *(const bf16x8*)(L + b32A + rdA + 3 * 2048 + o0);
    af1[1] = *(const bf16x8*)(L + b32A + rdA + 3 * 2048 + o1);
    if (pf) {
      if constexpr (NI == 3) {
        gload_lds16(sB + 128 * 1024 + kc, lwB + nbB + 16384);
        gload_lds16(sA + kc,              lwA + nbA);
      } else {
        gload_lds16(sA + kc,              lwA + nbA);
        gload_lds16(sA + 128 * 1024 + kc, lwA + nbA + 16384);
      }
    }
    __builtin_amdgcn_s_barrier();
    asm volatile("s_waitcnt lgkmcnt(0)" ::: "memory");
    __builtin_amdgcn_sched_barrier(0);
    __builtin_amdgcn_s_setprio(1);
    #pragma unroll
    for (int ks = 0; ks < 2; ++ks)
      #pragma unroll
      for (int ni = 0; ni < NI; ++ni) {
        acc[2][ni] = MFMA16(af0[ks], bfr[ni][ks], acc[2][ni]);
        acc[3][ni] = MFMA16(af1[ks], bfr[ni][ks], acc[3][ni]);
      }
    __builtin_amdgcn_s_setprio(0);
    if (pf) asm volatile("s_waitcnt vmcnt(4)" ::: "memory");
    else    asm volatile("s_waitcnt vmcnt(0)" ::: "memory");
    __builtin_amdgcn_s_barrier();
    asm volatile("" ::: "memory");

    // ================ phase 2: A mi{4,5}; stage (A2)|(A1) ================
    af0[0] = *(const bf16x8*)(L + b32A + rdA + 4 * 2048 + o0);
    af0[1] = *(const bf16x8*)(L + b32A + rdA + 4 * 2048 + o1);
    af1[0] = *(const bf16x8*)(L + b32A + rdA + 5 * 2048 + o0);
    af1[1] = *(const bf16x8*)(L + b32A + rdA + 5 * 2048 + o1);
    if (pf) {
      if constexpr (NI == 3)
        gload_lds16(sA + 128 * 1024 + kc, lwA + nbA + 16384);
      else
        gload_lds16(sA + 64 * 1024 + kc,  lwA + nbA + 8192);
    }
    __builtin_amdgcn_s_barrier();
    asm volatile("s_waitcnt lgkmcnt(0)" ::: "memory");
    __builtin_amdgcn_sched_barrier(0);
    __builtin_amdgcn_s_setprio(1);
    #pragma unroll
    for (int ks = 0; ks < 2; ++ks)
      #pragma unroll
      for (int ni = 0; ni < NI; ++ni) {
        acc[4][ni] = MFMA16(af0[ks], bfr[ni][ks], acc[4][ni]);
        acc[5][ni] = MFMA16(af1[ks], bfr[ni][ks], acc[5][ni]);
      }
    __builtin_amdgcn_s_setprio(0);
    __builtin_amdgcn_s_barrier();
    asm volatile("" ::: "memory");

    // ================ phase 3: A mi{6,7}; stage (A1,A3)|(A3); vmcnt(2) ================
    af0[0] = *(const bf16x8*)(L + b32A + rdA + 6 * 2048 + o0);
    af0[1] = *(const bf16x8*)(L + b32A + rdA + 6 * 2048 + o1);
    af1[0] = *(const bf16x8*)(L + b32A + rdA + 7 * 2048 + o0);
    af1[1] = *(const bf16x8*)(L + b32A + rdA + 7 * 2048 + o1);
    if (pf) {
      if constexpr (NI == 3) {
        gload_lds16(sA + 64 * 1024 + kc,  lwA + nbA + 8192);
        gload_lds16(sA + 192 * 1024 + kc, lwA + nbA + 24576);
      } else {
        gload_lds16(sA + 192 * 1024 + kc, lwA + nbA + 24576);
      }
    }
    __builtin_amdgcn_s_barrier();
    asm volatile("s_waitcnt lgkmcnt(0)" ::: "memory");
    __builtin_amdgcn_sched_barrier(0);
    __builtin_amdgcn_s_setprio(1);
    #pragma unroll
    for (int ks = 0; ks < 2; ++ks)
      #pragma unroll
      for (int ni = 0; ni < NI; ++ni) {
        acc[6][ni] = MFMA16(af0[ks], bfr[ni][ks], acc[6][ni]);
        acc[7][ni] = MFMA16(af1[ks], bfr[ni][ks], acc[7][ni]);
      }
    __builtin_amdgcn_s_setprio(0);
    if (pf) asm volatile("s_waitcnt vmcnt(2)" ::: "memory");
    __builtin_amdgcn_s_barrier();
    asm volatile("" ::: "memory");
  }

  // ---- epilogue ----
  if constexpr (F32OUT) {
    #pragma unroll
    for (int ni = 0; ni < NI; ++ni) {
      const int col = n0 + wc * WCOL + ni * 16 + lo;
      const float bv = bias[col];
      #pragma unroll
      for (int mi = 0; mi < 8; ++mi) {
        const int row = m0 + wr * 128 + mi * 16 + quad * 4;
        #pragma unroll
        for (int r = 0; r < 4; ++r)
          Cf[(size_t)(row + r) * 1024 + col] = acc[mi][ni][r] + bv;
      }
    }
  } else {
    #pragma unroll
    for (int ni = 0; ni < NI; ++ni) {
      const int colb = n0 + wc * WCOL + ni * 16;   // 16-aligned -> branch wave-uniform
      const float bv = bias[colb + lo];
      if (colb < 2048) {
        // Q,K part: dense [8192][2048] store
        const int col = colb + lo;
        #pragma unroll
        for (int mi = 0; mi < 8; ++mi) {
          const int row = m0 + wr * 128 + mi * 16 + quad * 4;
          #pragma unroll
          for (int r = 0; r < 4; ++r)
            QK[(size_t)(row + r) * 2048 + col] = f2bf(acc[mi][ni][r] + bv);
        }
      } else {
        // V part: permuted-transpose store into Vt[b][h][d][SEQ]
        const int vcol = colb + lo - 2048;
        const int hh = vcol >> 6, d = vcol & 63;
        #pragma unroll
        for (int mi = 0; mi < 8; ++mi) {
          const int base = m0 + wr * 128 + mi * 16;        // multiple of 16
          const int brow = base + quad * 4;                // 4 keys brow..brow+3
          const int bidx = brow >> 11;                     // batch
          const int srow = brow & 2047;                    // seq within batch
          const int ck   = srow >> 6;
          const int c0   = (base & 32) + (quad << 3) + ((base >> 2) & 4);
          ushort e0 = f2bf(acc[mi][ni][0] + bv);
          ushort e1 = f2bf(acc[mi][ni][1] + bv);
          ushort e2 = f2bf(acc[mi][ni][2] + bv);
          ushort e3 = f2bf(acc[mi][ni][3] + bv);
          uint2 pk;
          pk.x = (uint)e0 | ((uint)e1 << 16);
          pk.y = (uint)e2 | ((uint)e3 << 16);
          *(uint2*)&Vt[(size_t)((bidx * HEADS + hh) * HDIM + d) * SEQ + ck * 64 + c0] = pk;
        }
      }
    }
  }
}

// ---------- flash attention: block = 256 q rows, wave = 64 q (4 qg x 16), 64-key chunks ----------
// S^T via mfma(A=K,B=Q); exp'd scores feed PV A-operand directly from registers.
// Double-buffered K/V staging with counted vmcnt (T3/T14); XCD-grouped K/V reuse (T1);
// setprio around the PV MFMA cluster (T5).
__global__ __launch_bounds__(256, 2) void attn_kernel(const ushort* __restrict__ QK,
                                                      const ushort* __restrict__ Vt,
                                                      ushort* __restrict__ Og) {
  __shared__ __align__(16) ushort Ks[2][64 * 64];   // [buf][key][64 d], seg-swizzled
  __shared__ __align__(16) ushort Vs[2][64 * 64];   // [buf][d][64 key-slots], seg-swizzled

  const int tid  = threadIdx.x;
  const int w    = tid >> 6, lane = tid & 63;
  const int lo   = lane & 15, quad = lane >> 4;

  // XCD remap: p -> (G, qb); bijective, p&7 == G&7 (8 q-blocks of a group share an XCD)
  const int p  = blockIdx.x + (blockIdx.y << 3) + (blockIdx.z << 7);
  const int G  = ((p >> 6) << 3) | (p & 7);
  const int h  = G & 15, b = G >> 4;
  const int qbase = ((p >> 3) & 7) * 256 + w * 64;
  const int swz = lo & 7;

  // per-thread staging geometry (4 gload_lds16 per chunk: K0,V0,K1,V1)
  auto STAGE = [&](int buf, int ck) {
    #pragma unroll
    for (int i = 0; i < 2; ++i) {
      const int c16 = (w * 2 + i) * 64 + lane;
      const int r = c16 >> 3, ps = c16 & 7;
      const int gs = ps ^ (r & 7);
      gload_lds16(QK + (size_t)(b * SEQ + ck * 64 + r) * 2048 + 1024 + h * HDIM + gs * 8,
                  &Ks[buf][(w * 2 + i) * 512]);
      gload_lds16(Vt + (size_t)((b * HEADS + h) * HDIM + r) * SEQ + ck * 64 + gs * 8,
                  &Vs[buf][(w * 2 + i) * 512]);
    }
  };

  // Q fragments (B-operand layout: n=lo, k=quad*8+j); pre-scaled by QSCALE via Wq
  bf16x8 qf[4][2];
  #pragma unroll
  for (int qg = 0; qg < 4; ++qg) {
    const ushort* qp = QK + (size_t)(b * SEQ + qbase + qg * 16 + lo) * 2048 + h * HDIM;
    qf[qg][0] = *(const bf16x8*)(qp + quad * 8);
    qf[qg][1] = *(const bf16x8*)(qp + 32 + quad * 8);
  }

  f32x4 acc[4][4];
  #pragma unroll
  for (int qg = 0; qg < 4; ++qg)
    #pragma unroll
    for (int t = 0; t < 4; ++t) acc[qg][t] = {0.f, 0.f, 0.f, 0.f};
  float lsum[4] = {0.f, 0.f, 0.f, 0.f};

  // prologue: stage chunk 0 into buf 0; drain everything (incl. Q loads) once
  STAGE(0, 0);
  __syncthreads();

  #pragma unroll 2
  for (int ck = 0; ck < SEQ / 64; ++ck) {
    const int cur = ck & 1;
    if (ck < SEQ / 64 - 1) {
      STAGE(cur ^ 1, ck + 1);                           // issue-early (T14)
      asm volatile("s_waitcnt vmcnt(4)" ::: "memory");  // wait cur; next stays in flight
    } else {
      asm volatile("s_waitcnt vmcnt(0)" ::: "memory");
    }
    __builtin_amdgcn_s_barrier();
    asm volatile("" ::: "memory");

    // --- phase A: K fragments resident, S^T per q-group, exp + pack in registers ---
    bf16x8 kf[4][2];
    #pragma unroll
    for (int sub = 0; sub < 4; ++sub) {
      const ushort* kr = &Ks[cur][(sub * 16 + lo) * 64];
      kf[sub][0] = *(const bf16x8*)(kr + ((quad ^ swz) * 8));
      kf[sub][1] = *(const bf16x8*)(kr + (((4 + quad) ^ swz) * 8));
    }

    bf16x8 af[4][2];
    #pragma unroll
    for (int qg = 0; qg < 4; ++qg) {
      f32x4 s[4];
      #pragma unroll
      for (int sub = 0; sub < 4; ++sub) s[sub] = {0.f, 0.f, 0.f, 0.f};
      #pragma unroll
      for (int sub = 0; sub < 4; ++sub) {
        s[sub] = __builtin_amdgcn_mfma_f32_16x16x32_bf16(kf[sub][0], qf[qg][0], s[sub], 0, 0, 0);
        s[sub] = __builtin_amdgcn_mfma_f32_16x16x32_bf16(kf[sub][1], qf[qg][1], s[sub], 0, 0, 0);
      }
      float p2[4][4];
      #pragma unroll
      for (int sub = 0; sub < 4; ++sub)
        #pragma unroll
        for (int r = 0; r < 4; ++r) p2[sub][r] = __builtin_amdgcn_exp2f(s[sub][r]);
      float t0 = 0.f;
      #pragma unroll
      for (int sub = 0; sub < 4; ++sub)
        t0 += (p2[sub][0] + p2[sub][1]) + (p2[sub][2] + p2[sub][3]);
      lsum[qg] += t0;
      af[qg][0] = pack8(p2[0][0], p2[0][1], p2[0][2], p2[0][3], p2[1][0], p2[1][1], p2[1][2], p2[1][3]);
      af[qg][1] = pack8(p2[2][0], p2[2][1], p2[2][2], p2[2][3], p2[3][0], p2[3][1], p2[3][2], p2[3][3]);
    }

    // --- phase B: PV (A = exp'd scores from registers, B = V^T from LDS) ---
    __builtin_amdgcn_s_setprio(1);
    #pragma unroll
    for (int t = 0; t < 4; ++t) {
      const ushort* vr = &Vs[cur][(t * 16 + lo) * 64];
      #pragma unroll
      for (int hh = 0; hh < 2; ++hh) {
        bf16x8 vf = *(const bf16x8*)(vr + (((hh * 4 + quad) ^ swz) * 8));
        #pragma unroll
        for (int qg = 0; qg < 4; ++qg)
          acc[qg][t] = __builtin_amdgcn_mfma_f32_16x16x32_bf16(af[qg][hh], vf, acc[qg][t], 0, 0, 0);
      }
    }
    __builtin_amdgcn_s_setprio(0);

    asm volatile("" ::: "memory");
    __builtin_amdgcn_s_barrier();   // all reads of buf cur done before it is restaged
    asm volatile("" ::: "memory");
  }

  // --- epilogue: lsum lives at lane lo = q; reduce across quads, redistribute, store ---
  #pragma unroll
  for (int qg = 0; qg < 4; ++qg) {
    float v = lsum[qg];
    v += __shfl_xor(v, 16);
    v += __shfl_xor(v, 32);
    float linv[4];
    #pragma unroll
    for (int r = 0; r < 4; ++r) linv[r] = 1.0f / __shfl(v, quad * 4 + r);
    #pragma unroll
    for (int t = 0; t < 4; ++t)
      #pragma unroll
      for (int r = 0; r < 4; ++r)
        Og[(size_t)(b * SEQ + qbase + qg * 16 + quad * 4 + r) * D_MODEL + h * HDIM + t * 16 + lo] =
            f2bf(acc[qg][t][r] * linv[r]);
  }
}

extern "C" void kernel_launch(void* const* d_in, const int* in_sizes, int n_in,
                              void* d_out, int out_size, void* d_ws, size_t ws_size,
                              hipStream_t stream) {
  const float* X  = (const float*)d_in[0];
  const float* Wq = (const float*)d_in[1];
  const float* bq = (const float*)d_in[2];
  const float* Wk = (const float*)d_in[3];
  const float* bk = (const float*)d_in[4];
  const float* Wv = (const float*)d_in[5];
  const float* bv = (const float*)d_in[6];
  const float* Wo = (const float*)d_in[7];
  const float* bo = (const float*)d_in[8];
  float* out = (float*)d_out;
  char* ws = (char*)d_ws;

  // workspace (88 MB):
  //   [0,16M)   Xb  (bf16 X)
  //   [16,24M)  WT  (4x bf16 transposed weights q|k|v|o; Wq pre-scaled)
  //   [24,56M)  QK  bf16 [8192][2048]
  //   [56,72M)  Vt  bf16 [b][h][64][2048] (permuted keys)
  //   [72,88M)  Ob  bf16 [8192][1024]; head transiently holds bcat (dead before attn writes Ob)
  ushort* Xb  = (ushort*)(ws);
  ushort* WT  = (ushort*)(ws + 16777216);
  ushort* QKb = (ushort*)(ws + 25165824);
  ushort* Vtb = (ushort*)(ws + 58720256);
  ushort* Ob  = (ushort*)(ws + 75497472);
  float*  bcat = (float*)(ws + 75497472);
  const int WSTRIDE = D_MODEL * D_MODEL;

  // 1) fused prep: X->bf16, weight transposes, bias concat
  prep_kernel<<<12300, 256, 0, stream>>>(X, Wq, Wk, Wv, Wo, bq, bk, bv, Xb, WT, bcat);

  // 2) fused QKV projection: 256x192 tiles -> 512 blocks = 2 exact rounds on 256 CUs
  gemm8p<192, false><<<dim3(16, 32), 512, 0, stream>>>(Xb, WT, bcat, QKb, Vtb, nullptr);

  // 3) flash attention (double-buffered staging + XCD-grouped K/V reuse)
  attn_kernel<<<dim3(SEQ / 256, HEADS, BATCH), 256, 0, stream>>>(QKb, Vtb, Ob);

  // 4) output projection: 256x128 tiles -> 256 blocks = 1 exact round, fp32 out + bias
  gemm8p<128, true><<<dim3(8, 32), 512, 0, stream>>>(Ob, WT + 3 * WSTRIDE, bo, nullptr, nullptr, out);
}